// Round 17
// baseline (85.485 us; speedup 1.0000x reference)
//
#include <hip/hip_runtime.h>
#include <hip/hip_bf16.h>

typedef __attribute__((ext_vector_type(8))) short short8;   // 8 bf16 (4 VGPRs)
typedef __attribute__((ext_vector_type(4))) float f32x4;    // MFMA acc

// Problem constants
static constexpr int HW = 1024;   // 32*32
static constexpr int C2 = 160;    // corr channel count
static constexpr int FS = 168;    // conv epilogue LDS row stride (shorts)
static constexpr int FSC = 160;   // corr LDS row stride (shorts) — gload-compatible
static constexpr int KSTEPS = 10;
static constexpr int XST = 264;   // conv xF octet-block stride in floats
static constexpr int XBUF = 9504; // floats per xF buffer (36 * XST)
static constexpr size_t PL = 32ull * 1024 * 160;   // shorts per f-plane (10.49MB)
static constexpr size_t PPL = 32ull * 256 * 160;   // shorts per pooled plane
static constexpr int AIMG = 6656;  // shorts per (ks,qp) A-image (12800 B data + 512 B pad)

__device__ inline short bfh(float v) {
  __hip_bfloat16 h = __float2bfloat16(v);
  return *reinterpret_cast<short*>(&h);
}
__device__ inline float bff(short s) {
  union { unsigned u; float f; } c;
  c.u = ((unsigned)(unsigned short)s) << 16;
  return c.f;
}

// async global->LDS, 16 B per lane: per-lane global src, wave-uniform LDS base
typedef const __attribute__((address_space(1))) void* gas_t;
typedef __attribute__((address_space(3))) void* las_t;
__device__ inline void gload_lds16(const void* g, void* l) {
  __builtin_amdgcn_global_load_lds((gas_t)g, (las_t)l, 16, 0, 0);
}

// ---------------------------------------------------------------------------
// Kernel 0: pre-split w into bf16 (hi,lo), one contiguous 13312 B image per
// (ks,qp) matching conv's aL layout [hl 2][gr 80][kk 40] (unchanged).
// ---------------------------------------------------------------------------
__global__ __launch_bounds__(256)
void wprep2_kernel(const float* __restrict__ w0, const float* __restrict__ w1,
                   short* __restrict__ wp) {
  const int id = blockIdx.x * 256 + threadIdx.x;
  if (id >= KSTEPS * 4 * AIMG) return;
  const int img = id / AIMG, r = id % AIMG;
  const int ks = img >> 2, qp = img & 3;
  short outv = 0;
  if (r < 6400) {
    const int hl = r / 3200;
    const int g2 = r % 3200;
    const int gr = g2 / 40, kk = g2 % 40;
    const int mat = gr >= 40;
    const int o = qp * 40 + gr - mat * 40;
    if (kk < 32) {
      const float v = (mat ? w1 : w0)[o * 320 + ks * 32 + kk];
      const short hb = bfh(v);
      outv = hl ? bfh(v - bff(hb)) : hb;
    }
  }
  wp[id] = outv;
}

// ---------------------------------------------------------------------------
// Kernel 1 (ROUND-17): round-16 conv with a COUNTED-VMCNT double-buffered
// pipeline (T3+T4). Per ks: ISSUE(ks+1 -> buf^1); per-wave
// s_waitcnt vmcnt(count of ks+1 loads) so ks+1's gloads STAY IN FLIGHT across
// the raw s_barrier; MFMA(ks, buf); trailing s_barrier (WAR on buf).
// Distributed drain: each wave waits its own ks loads; barrier => all landed.
// Per-wave gload counts (A + x): w0-3: 7, w4-5: 6, w6: 5, w7: 4.
// LDS: xF dbuf 2*38016 + aL dbuf 2*13312 = 102656 B -> 1 block/CU; intra-block
// pipelining replaces cross-block hiding. All other code = round 16 verbatim.
// ---------------------------------------------------------------------------
__global__ __launch_bounds__(512)
void conv_fused(const float* __restrict__ x, const short* __restrict__ wprep2,
                short* __restrict__ f0bh, short* __restrict__ f0bl,
                short* __restrict__ f1bh, short* __restrict__ f1bl) {
  __shared__ __align__(16) char lds[102656];
  float* xF = reinterpret_cast<float*>(lds);            // [2][36] @ stride XST
  short* aL = reinterpret_cast<short*>(lds + 76032);    // [2][AIMG]
  short* tL = reinterpret_cast<short*>(lds);            // epilogue [2][64][168]

  const int pxt = blockIdx.x;  // 0..31 (32-px tile)
  const int qp = blockIdx.y;   // 0..3
  const int bb = blockIdx.z;   // 0..3
  const int tid = threadIdx.x;
  const int lane = tid & 63;
  const int wave = __builtin_amdgcn_readfirstlane(tid >> 6);  // 0..7
  const int lr = lane & 15, kg = lane >> 4;
  const int fgrp = wave >> 1;  // 0..3: f in {fgrp, fgrp+4, fgrp+8}
  const int pxh = wave & 1;    // px half (16)

  const int l8 = lane >> 3;    // x-gload: row (c) within octet
  const int l7 = lane & 7;     // x-gload: 16B chunk within 128B px-row
  const int px = pxh * 16 + lr;
  const int pxs = px ^ (kg << 3);  // swizzled read column (matches src swizzle)

  f32x4 acc[5][3];
#pragma unroll
  for (int mt = 0; mt < 5; ++mt)
#pragma unroll
    for (int fi = 0; fi < 3; ++fi)
#pragma unroll
      for (int r = 0; r < 4; ++r) acc[mt][fi][r] = 0.f;

  const float* xg = x + ((size_t)(bb * 320) * 9) * 1024 + (size_t)pxt * 32;

#define ISSUE(KS, BUF)                                                        \
  {                                                                           \
    const short* asrc = wprep2 + (size_t)((KS) * 4 + qp) * AIMG;              \
    _Pragma("unroll") for (int jj = 0; jj < 2; ++jj) {                        \
      const int j = wave * 2 + jj;                                            \
      if (j < 13)                                                             \
        gload_lds16(asrc + j * 512 + lane * 8, aL + (BUF) * AIMG + j * 512);  \
    }                                                                         \
    _Pragma("unroll") for (int jj = 0; jj < 5; ++jj) {                        \
      const int gi = wave + jj * 8;                                           \
      if (gi < 36) {                                                          \
        const int f_ = gi >> 2, oct_ = gi & 3;                                \
        const int c_ = (KS) * 32 + oct_ * 8 + l8;                             \
        gload_lds16(xg + ((size_t)c_ * 9 + f_) * 1024 + ((l7 ^ (oct_ << 1)) << 2), \
                    xF + (BUF) * XBUF + gi * XST);                            \
      }                                                                       \
    }                                                                         \
  }

  // prologue: issue ks=0 into buffer 0
  ISSUE(0, 0);

#pragma unroll
  for (int ks = 0; ks < KSTEPS; ++ks) {
    const int buf = ks & 1;
    if (ks + 1 < KSTEPS) {
      ISSUE(ks + 1, buf ^ 1);  // safe: trailing barrier of prev iter done
      // wait for ks's loads only (ks+1's stay in flight across the barrier)
      if (wave < 4)       asm volatile("s_waitcnt vmcnt(7)" ::: "memory");
      else if (wave < 6)  asm volatile("s_waitcnt vmcnt(6)" ::: "memory");
      else if (wave == 6) asm volatile("s_waitcnt vmcnt(5)" ::: "memory");
      else                asm volatile("s_waitcnt vmcnt(4)" ::: "memory");
    } else {
      asm volatile("s_waitcnt vmcnt(0)" ::: "memory");
    }
    __builtin_amdgcn_s_barrier();       // all waves' ks data in LDS
    __builtin_amdgcn_sched_barrier(0);  // pin LDS reads below the barrier

    // ---- MFMA phase on buffer `buf` ----
    const short* aB = aL + buf * AIMG;
    const float* xB = xF + buf * XBUF;
    short8 Ah[5], Al[5];
#pragma unroll
    for (int mt = 0; mt < 5; ++mt) {
      Ah[mt] = *reinterpret_cast<const short8*>(&aB[(mt * 16 + lr) * 40 + kg * 8]);
      Al[mt] = *reinterpret_cast<const short8*>(&aB[3200 + (mt * 16 + lr) * 40 + kg * 8]);
    }
#pragma unroll
    for (int fi = 0; fi < 3; ++fi) {
      const int f = fgrp + fi * 4;
      if (f < 9) {  // wave-uniform
        const float* bp = xB + (f * 4 + kg) * XST + pxs;
        float xv[8];
#pragma unroll
        for (int j = 0; j < 8; ++j) xv[j] = bp[j * 32];
        short8 Bh, Bl;
#pragma unroll
        for (int j = 0; j < 8; ++j) {
          const short h = bfh(xv[j]);
          Bh[j] = h;
          Bl[j] = bfh(xv[j] - bff(h));
        }
#pragma unroll
        for (int mt = 0; mt < 5; ++mt) {
          acc[mt][fi] = __builtin_amdgcn_mfma_f32_16x16x32_bf16(Ah[mt], Bh, acc[mt][fi], 0, 0, 0);
          acc[mt][fi] = __builtin_amdgcn_mfma_f32_16x16x32_bf16(Ah[mt], Bl, acc[mt][fi], 0, 0, 0);
          acc[mt][fi] = __builtin_amdgcn_mfma_f32_16x16x32_bf16(Al[mt], Bh, acc[mt][fi], 0, 0, 0);
        }
      }
    }
    __builtin_amdgcn_s_barrier();  // all waves done reading buf (WAR guard)
  }
#undef ISSUE

  // ---- epilogue: two mat-passes through LDS transpose (round-16 verbatim) ----
#pragma unroll
  for (int m = 0; m < 2; ++m) {
    __syncthreads();  // previous readers of xF/aL/tL done
#pragma unroll
    for (int mt = 0; mt < 5; ++mt)
#pragma unroll
      for (int fi = 0; fi < 3; ++fi) {
        const int f = fgrp + fi * 4;
        const int tt = f - m;
        if (f < 9 && (unsigned)tt < 8u) {
#pragma unroll
          for (int rr = 0; rr < 4; ++rr) {
            const int gr = mt * 16 + kg * 4 + rr;
            if ((gr >= 40) == (m == 1)) {  // row belongs to this mat
              const int rowl = gr - m * 40;
              const int ql = rowl / 20, r20 = rowl % 20;
              const int c = 8 * r20 + tt;
              const int row = ql * 32 + pxh * 16 + lr;
              const float v = acc[mt][fi][rr];
              const short h = bfh(v);
              tL[row * FS + c] = h;
              tL[10752 + row * FS + c] = bfh(v - bff(h));
            }
          }
        }
      }
    __syncthreads();
    // coalesced copy-out: 2560 uint4 over 512 threads
#pragma unroll
    for (int i = 0; i < 5; ++i) {
      const int idx = tid + i * 512;
      const int plane = idx / 1280, rem = idx % 1280;
      const int row = rem / 20, c16 = rem % 20;
      const int ql = row >> 5, pxl = row & 31;
      const int n = bb * 8 + qp * 2 + ql;
      short* dst = (m == 0) ? (plane ? f0bl : f0bh) : (plane ? f1bl : f1bh);
      *reinterpret_cast<uint4*>(dst + ((size_t)n * 1024 + pxt * 32 + pxl) * 160 + c16 * 8) =
          *reinterpret_cast<const uint4*>(&tL[plane * 10752 + row * FS + c16 * 8]);
    }
  }
}

// ---------------------------------------------------------------------------
// Kernel 2: 2x2 avg-pool on the bf16 h/l planes (unchanged)
// ---------------------------------------------------------------------------
__global__ __launch_bounds__(256)
void pool_b(const short* __restrict__ f1bh, const short* __restrict__ f1bl,
            short* __restrict__ g1pbh, short* __restrict__ g1pbl) {
  const int id = blockIdx.x * 256 + threadIdx.x;  // 32*256*20
  if (id >= 32 * 256 * 20) return;
  const int c16 = id % 20;
  const int PX = (id / 20) & 255;
  const int n = id / (20 * 256);
  const int Y = PX >> 4, X = PX & 15;
  const int r0 = Y * 64 + X * 2;
  const size_t base = ((size_t)n * 1024 + r0) * 160 + c16 * 8;
  const short8 h00 = *reinterpret_cast<const short8*>(f1bh + base);
  const short8 h01 = *reinterpret_cast<const short8*>(f1bh + base + 160);
  const short8 h10 = *reinterpret_cast<const short8*>(f1bh + base + 32 * 160);
  const short8 h11 = *reinterpret_cast<const short8*>(f1bh + base + 33 * 160);
  const short8 l00 = *reinterpret_cast<const short8*>(f1bl + base);
  const short8 l01 = *reinterpret_cast<const short8*>(f1bl + base + 160);
  const short8 l10 = *reinterpret_cast<const short8*>(f1bl + base + 32 * 160);
  const short8 l11 = *reinterpret_cast<const short8*>(f1bl + base + 33 * 160);
  short8 ho, lo;
#pragma unroll
  for (int j = 0; j < 8; ++j) {
    const float v = 0.25f * ((bff(h00[j]) + bff(l00[j])) + (bff(h01[j]) + bff(l01[j])) +
                             (bff(h10[j]) + bff(l10[j])) + (bff(h11[j]) + bff(l11[j])));
    const short h = bfh(v);
    ho[j] = h;
    lo[j] = bfh(v - bff(h));
  }
  const size_t ob = ((size_t)n * 256 + PX) * 160 + c16 * 8;
  *reinterpret_cast<short8*>(g1pbh + ob) = ho;
  *reinterpret_cast<short8*>(g1pbl + ob) = lo;
}

// ---------------------------------------------------------------------------
// Kernel 3: correlation via split-bf16 MFMA with gload staging
// (unchanged from round 11 — verified; XCD swizzle kept)
// ---------------------------------------------------------------------------
__global__ __launch_bounds__(256)
void corr_kernel(const short* __restrict__ f0bh, const short* __restrict__ f0bl,
                 const short* __restrict__ f1bh, const short* __restrict__ f1bl,
                 const short* __restrict__ g1pbh, const short* __restrict__ g1pbl,
                 float* __restrict__ out) {
  __shared__ __align__(16) short f0L[2][32 * FSC];
  __shared__ __align__(16) short f1L[2][32 * FSC];
  __shared__ float S0[32 * 33];
  __shared__ float S1[2][32 * 17];
  const int flat = blockIdx.x;
  const int xcd = flat & 7;
  const int rr_ = flat >> 3;
  const int y = rr_ & 31;                 // 0..31
  const int n = (xcd << 2) | (rr_ >> 5);  // 0..31
  const int bb = n >> 3, q = n & 7;
  const int tid = threadIdx.x;
  const int lane = tid & 63;
  const int wave = __builtin_amdgcn_readfirstlane(tid >> 6);
  const int lr = lane & 15, kg = lane >> 4;
  const int xx = tid & 31;
  const int hi = tid >> 5;  // 0..7
  const float inv = 1.f / 160.f;
  const size_t obase = (size_t)(bb * 784 + q) * 1024 + (size_t)y * 32;

  // ---- stage f0 row: 20 gloads ----
  {
    const short* s0 = f0bh + ((size_t)n * 1024 + y * 32) * 160;
    const short* s1 = f0bl + ((size_t)n * 1024 + y * 32) * 160;
#pragma unroll
    for (int jj = 0; jj < 5; ++jj) {
      const int j = wave * 5 + jj;  // 0..19
      const int pl = j / 10, off = (j % 10) * 512;
      gload_lds16((pl ? s1 : s0) + off + lane * 8, &f0L[pl][off]);
    }
  }
  __syncthreads();

  // ---- hoist A-fragments ----
  const int mi0 = wave >> 1, ni0 = wave & 1;
  short8 a0h[5], a0l[5];
#pragma unroll
  for (int ks = 0; ks < 5; ++ks) {
    a0h[ks] = *reinterpret_cast<const short8*>(&f0L[0][(mi0 * 16 + lr) * FSC + ks * 32 + kg * 8]);
    a0l[ks] = *reinterpret_cast<const short8*>(&f0L[1][(mi0 * 16 + lr) * FSC + ks * 32 + kg * 8]);
  }

  // ---- level 0 ----
  for (int dyi = 0; dyi < 7; ++dyi) {
    const int yy = y + dyi - 3;
    const bool inr = (unsigned)yy < 32u;
    __syncthreads();
    if (inr) {
      const short* s0 = f1bh + ((size_t)n * 1024 + yy * 32) * 160;
      const short* s1 = f1bl + ((size_t)n * 1024 + yy * 32) * 160;
#pragma unroll
      for (int jj = 0; jj < 5; ++jj) {
        const int j = wave * 5 + jj;
        const int pl = j / 10, off = (j % 10) * 512;
        gload_lds16((pl ? s1 : s0) + off + lane * 8, &f1L[pl][off]);
      }
    }
    __syncthreads();
    if (inr) {
      f32x4 aA = {0.f, 0.f, 0.f, 0.f}, aB = aA, aC = aA;
#pragma unroll
      for (int ks = 0; ks < 5; ++ks) {
        const short8 bh = *reinterpret_cast<const short8*>(&f1L[0][(ni0 * 16 + lr) * FSC + ks * 32 + kg * 8]);
        const short8 bl = *reinterpret_cast<const short8*>(&f1L[1][(ni0 * 16 + lr) * FSC + ks * 32 + kg * 8]);
        aA = __builtin_amdgcn_mfma_f32_16x16x32_bf16(a0h[ks], bh, aA, 0, 0, 0);
        aB = __builtin_amdgcn_mfma_f32_16x16x32_bf16(a0h[ks], bl, aB, 0, 0, 0);
        aC = __builtin_amdgcn_mfma_f32_16x16x32_bf16(a0l[ks], bh, aC, 0, 0, 0);
      }
#pragma unroll
      for (int r = 0; r < 4; ++r)
        S0[(mi0 * 16 + kg * 4 + r) * 33 + ni0 * 16 + lr] = (aA[r] + aB[r]) + aC[r];
    }
    __syncthreads();
    if (hi < 7) {
      const int x2 = xx + hi - 3;
      const float val = (inr && (unsigned)x2 < 32u) ? S0[xx * 33 + x2] * inv : 0.f;
      out[obase + (size_t)(hi * 7 + dyi) * 8192 + xx] = val;
    }
  }

  // ---- level 1: corner dots on pooled planes, rolling S1 + fused combine ----
  short8 a1h[5], a1l[5];
  if (wave < 2) {
#pragma unroll
    for (int ks = 0; ks < 5; ++ks) {
      a1h[ks] = *reinterpret_cast<const short8*>(&f0L[0][(wave * 16 + lr) * FSC + ks * 32 + kg * 8]);
      a1l[ks] = *reinterpret_cast<const short8*>(&f0L[1][(wave * 16 + lr) * FSC + ks * 32 + kg * 8]);
    }
  }
  const int Y0 = (y >> 1) - 3;
  const float wy = (y & 1) ? 0.5f : 0.f;
  for (int v = 0; v < 8; ++v) {
    const int Y = Y0 + v;
    const bool inr = (unsigned)Y < 16u;
    __syncthreads();
    if (inr) {
      const short* s0 = g1pbh + ((size_t)n * 256 + Y * 16) * 160;
      const short* s1 = g1pbl + ((size_t)n * 256 + Y * 16) * 160;
#pragma unroll
      for (int jj = 0; jj < 3; ++jj) {
        const int j = wave * 3 + jj;  // 0..11
        if (j < 10) {
          const int pl = j / 5, off = (j % 5) * 512;
          gload_lds16((pl ? s1 : s0) + off + lane * 8, &f1L[pl][off]);
        }
      }
    }
    __syncthreads();
    if (wave < 2) {
      f32x4 aA = {0.f, 0.f, 0.f, 0.f}, aB = aA, aC = aA;
      if (inr) {
#pragma unroll
        for (int ks = 0; ks < 5; ++ks) {
          const short8 bh = *reinterpret_cast<const short8*>(&f1L[0][lr * FSC + ks * 32 + kg * 8]);
          const short8 bl = *reinterpret_cast<const short8*>(&f1L[1][lr * FSC + ks * 32 + kg * 8]);
          aA = __builtin_amdgcn_mfma_f32_16x16x32_bf16(a1h[ks], bh, aA, 0, 0, 0);
          aB = __builtin_amdgcn_mfma_f32_16x16x32_bf16(a1h[ks], bl, aB, 0, 0, 0);
          aC = __builtin_amdgcn_mfma_f32_16x16x32_bf16(a1l[ks], bh, aC, 0, 0, 0);
        }
      }
#pragma unroll
      for (int r = 0; r < 4; ++r)
        S1[v & 1][(wave * 16 + kg * 4 + r) * 17 + lr] = (aA[r] + aB[r]) + aC[r];
    }
    __syncthreads();
    if (v >= 1 && hi < 7) {
      const int dyi = v - 1;
      const int Xl = (xx >> 1) - 3 + hi;
      const int Xr = Xl + 1;
      const float* t0 = S1[(v - 1) & 1];
      const float* t1 = S1[v & 1];
      const float a00 = ((unsigned)Xl < 16u) ? t0[xx * 17 + Xl] : 0.f;
      const float a01 = ((unsigned)Xr < 16u) ? t0[xx * 17 + Xr] : 0.f;
      const float a10 = ((unsigned)Xl < 16u) ? t1[xx * 17 + Xl] : 0.f;
      const float a11 = ((unsigned)Xr < 16u) ? t1[xx * 17 + Xr] : 0.f;
      const float wx = (xx & 1) ? 0.5f : 0.f;
      const float val = ((1.f - wx) * ((1.f - wy) * a00 + wy * a10) +
                         wx * ((1.f - wy) * a01 + wy * a11)) * inv;
      out[obase + (size_t)(49 + hi * 7 + dyi) * 8192 + xx] = val;
    }
  }
}

// ---------------------------------------------------------------------------
extern "C" void kernel_launch(void* const* d_in, const int* in_sizes, int n_in,
                              void* d_out, int out_size, void* d_ws,
                              size_t ws_size, hipStream_t stream) {
  const float* x = (const float*)d_in[0];
  const float* w0 = (const float*)d_in[1];
  const float* w1 = (const float*)d_in[2];
  short* f0bh = (short*)d_ws;
  short* f0bl = f0bh + PL;
  short* f1bh = f0bl + PL;
  short* f1bl = f1bh + PL;
  short* g1pbh = f1bl + PL;
  short* g1pbl = g1pbh + PPL;
  short* wprep2 = g1pbh;  // overlapped: consumed by conv before pool writes
  float* out = (float*)d_out;

  wprep2_kernel<<<1040, 256, 0, stream>>>(w0, w1, wprep2);
  conv_fused<<<dim3(32, 4, 4), 512, 0, stream>>>(x, wprep2, f0bh, f0bl, f1bh, f1bl);
  pool_b<<<640, 256, 0, stream>>>(f1bh, f1bl, g1pbh, g1pbl);
  corr_kernel<<<1024, 256, 0, stream>>>(f0bh, f0bl, f1bh, f1bl, g1pbh, g1pbl, out);
}

// Round 18
// 76.563 us; speedup vs baseline: 1.1165x; 1.1165x over previous
//
#include <hip/hip_runtime.h>
#include <hip/hip_bf16.h>

typedef __attribute__((ext_vector_type(8))) short short8;   // 8 bf16 (4 VGPRs)
typedef __attribute__((ext_vector_type(4))) float f32x4;    // MFMA acc

// Problem constants
static constexpr int HW = 1024;   // 32*32
static constexpr int C2 = 160;    // corr channel count
static constexpr int FS = 168;    // conv epilogue LDS row stride (shorts)
static constexpr int FSC = 160;   // corr LDS row stride (shorts) — gload-compatible
static constexpr int KSTEPS = 10;
static constexpr int XST = 264;   // conv xF octet-block stride in floats (1056 B)
static constexpr size_t PL = 32ull * 1024 * 160;   // shorts per f-plane (10.49MB)
static constexpr size_t PPL = 32ull * 256 * 160;   // shorts per pooled plane
static constexpr int AIMG = 6656;  // shorts per (ks,qp) A-image (12800 B data + 512 B pad)

__device__ inline short bfh(float v) {
  __hip_bfloat16 h = __float2bfloat16(v);
  return *reinterpret_cast<short*>(&h);
}
__device__ inline float bff(short s) {
  union { unsigned u; float f; } c;
  c.u = ((unsigned)(unsigned short)s) << 16;
  return c.f;
}

// async global->LDS, 16 B per lane: per-lane global src, wave-uniform LDS base
// (HW adds lane*16 to dest). Drained by the vmcnt(0) before s_barrier.
typedef const __attribute__((address_space(1))) void* gas_t;
typedef __attribute__((address_space(3))) void* las_t;
__device__ inline void gload_lds16(const void* g, void* l) {
  __builtin_amdgcn_global_load_lds((gas_t)g, (las_t)l, 16, 0, 0);
}

// ---------------------------------------------------------------------------
// Kernel 0: pre-split w into bf16 (hi,lo), one contiguous 13312 B image per
// (ks,qp) matching conv's aL layout [hl 2][gr 80][kk 40].
// ---------------------------------------------------------------------------
__global__ __launch_bounds__(256)
void wprep2_kernel(const float* __restrict__ w0, const float* __restrict__ w1,
                   short* __restrict__ wp) {
  const int id = blockIdx.x * 256 + threadIdx.x;
  if (id >= KSTEPS * 4 * AIMG) return;
  const int img = id / AIMG, r = id % AIMG;
  const int ks = img >> 2, qp = img & 3;
  short outv = 0;
  if (r < 6400) {
    const int hl = r / 3200;
    const int g2 = r % 3200;
    const int gr = g2 / 40, kk = g2 % 40;
    const int mat = gr >= 40;
    const int o = qp * 40 + gr - mat * 40;
    if (kk < 32) {
      const float v = (mat ? w1 : w0)[o * 320 + ks * 32 + kk];
      const short hb = bfh(v);
      outv = hl ? bfh(v - bff(hb)) : hb;
    }
  }
  wp[id] = outv;
}

// ---------------------------------------------------------------------------
// Kernel 1 (= round 16, measured champion): 512 thr, 32-px tile, single-
// buffered gload staging; xF octet blocks at stride XST=264 floats.
// ---------------------------------------------------------------------------
__global__ __launch_bounds__(512)
void conv_fused(const float* __restrict__ x, const short* __restrict__ wprep2,
                short* __restrict__ f0bh, short* __restrict__ f0bl,
                short* __restrict__ f1bh, short* __restrict__ f1bl) {
  __shared__ __align__(16) char lds[51296];
  float* xF = reinterpret_cast<float*>(lds);            // [gi 36] @ stride XST
  short* aL = reinterpret_cast<short*>(lds + 37984);    // [hl 2][gr 80][kk 40]
  short* tL = reinterpret_cast<short*>(lds);            // epilogue [2][64][168]

  const int pxt = blockIdx.x;  // 0..31 (32-px tile)
  const int qp = blockIdx.y;   // 0..3
  const int bb = blockIdx.z;   // 0..3
  const int tid = threadIdx.x;
  const int lane = tid & 63;
  const int wave = __builtin_amdgcn_readfirstlane(tid >> 6);  // 0..7
  const int lr = lane & 15, kg = lane >> 4;
  const int fgrp = wave >> 1;  // 0..3: f in {fgrp, fgrp+4, fgrp+8}
  const int pxh = wave & 1;    // px half (16)

  const int l8 = lane >> 3;    // x-gload: row (c) within octet
  const int l7 = lane & 7;     // x-gload: 16B chunk within 128B px-row
  const int px = pxh * 16 + lr;
  const int pxs = px ^ (kg << 3);  // swizzled read column (matches src swizzle)

  f32x4 acc[5][3];
#pragma unroll
  for (int mt = 0; mt < 5; ++mt)
#pragma unroll
    for (int fi = 0; fi < 3; ++fi)
#pragma unroll
      for (int r = 0; r < 4; ++r) acc[mt][fi][r] = 0.f;

  const float* xg = x + ((size_t)(bb * 320) * 9) * 1024 + (size_t)pxt * 32;

  for (int ks = 0; ks < KSTEPS; ++ks) {
    if (ks) __syncthreads();  // previous xF/aL readers done
    // ---- A: 13 gloads (wave w: j = w*2, w*2+1) ----
    {
      const short* asrc = wprep2 + (size_t)(ks * 4 + qp) * AIMG;
#pragma unroll
      for (int jj = 0; jj < 2; ++jj) {
        const int j = wave * 2 + jj;
        if (j < 13) gload_lds16(asrc + j * 512 + lane * 8, aL + j * 512);
      }
    }
    // ---- x: 36 gloads (wave w: gi = w, w+8, ..., w+32; gi = f*4 + oct) ----
#pragma unroll
    for (int jj = 0; jj < 5; ++jj) {
      const int gi = wave + jj * 8;
      if (gi < 36) {
        const int f = gi >> 2, oct = gi & 3;
        const int c = ks * 32 + oct * 8 + l8;
        const float* src =
            xg + ((size_t)c * 9 + f) * 1024 + ((l7 ^ (oct << 1)) << 2);
        gload_lds16(src, xF + gi * XST);
      }
    }
    __syncthreads();  // implicit vmcnt(0): all gloads landed

    // ---- MFMA phase ----
    short8 Ah[5], Al[5];
#pragma unroll
    for (int mt = 0; mt < 5; ++mt) {
      Ah[mt] = *reinterpret_cast<const short8*>(&aL[(mt * 16 + lr) * 40 + kg * 8]);
      Al[mt] = *reinterpret_cast<const short8*>(&aL[3200 + (mt * 16 + lr) * 40 + kg * 8]);
    }
#pragma unroll
    for (int fi = 0; fi < 3; ++fi) {
      const int f = fgrp + fi * 4;
      if (f < 9) {  // wave-uniform
        const float* bp = xF + (f * 4 + kg) * XST + pxs;
        float xv[8];
#pragma unroll
        for (int j = 0; j < 8; ++j) xv[j] = bp[j * 32];
        short8 Bh, Bl;
#pragma unroll
        for (int j = 0; j < 8; ++j) {
          const short h = bfh(xv[j]);
          Bh[j] = h;
          Bl[j] = bfh(xv[j] - bff(h));
        }
#pragma unroll
        for (int mt = 0; mt < 5; ++mt) {
          acc[mt][fi] = __builtin_amdgcn_mfma_f32_16x16x32_bf16(Ah[mt], Bh, acc[mt][fi], 0, 0, 0);
          acc[mt][fi] = __builtin_amdgcn_mfma_f32_16x16x32_bf16(Ah[mt], Bl, acc[mt][fi], 0, 0, 0);
          acc[mt][fi] = __builtin_amdgcn_mfma_f32_16x16x32_bf16(Al[mt], Bh, acc[mt][fi], 0, 0, 0);
        }
      }
    }
  }

  // ---- epilogue: two mat-passes through LDS transpose ----
#pragma unroll
  for (int m = 0; m < 2; ++m) {
    __syncthreads();  // previous readers of xF/aL/tL done
#pragma unroll
    for (int mt = 0; mt < 5; ++mt)
#pragma unroll
      for (int fi = 0; fi < 3; ++fi) {
        const int f = fgrp + fi * 4;
        const int tt = f - m;
        if (f < 9 && (unsigned)tt < 8u) {
#pragma unroll
          for (int rr = 0; rr < 4; ++rr) {
            const int gr = mt * 16 + kg * 4 + rr;
            if ((gr >= 40) == (m == 1)) {  // row belongs to this mat
              const int rowl = gr - m * 40;
              const int ql = rowl / 20, r20 = rowl % 20;
              const int c = 8 * r20 + tt;
              const int row = ql * 32 + pxh * 16 + lr;
              const float v = acc[mt][fi][rr];
              const short h = bfh(v);
              tL[row * FS + c] = h;
              tL[10752 + row * FS + c] = bfh(v - bff(h));
            }
          }
        }
      }
    __syncthreads();
    // coalesced copy-out: 2560 uint4 over 512 threads
#pragma unroll
    for (int i = 0; i < 5; ++i) {
      const int idx = tid + i * 512;
      const int plane = idx / 1280, rem = idx % 1280;
      const int row = rem / 20, c16 = rem % 20;
      const int ql = row >> 5, pxl = row & 31;
      const int n = bb * 8 + qp * 2 + ql;
      short* dst = (m == 0) ? (plane ? f0bl : f0bh) : (plane ? f1bl : f1bh);
      *reinterpret_cast<uint4*>(dst + ((size_t)n * 1024 + pxt * 32 + pxl) * 160 + c16 * 8) =
          *reinterpret_cast<const uint4*>(&tL[plane * 10752 + row * FS + c16 * 8]);
    }
  }
}

// ---------------------------------------------------------------------------
// Kernel 2: 2x2 avg-pool on the bf16 h/l planes (unchanged)
// ---------------------------------------------------------------------------
__global__ __launch_bounds__(256)
void pool_b(const short* __restrict__ f1bh, const short* __restrict__ f1bl,
            short* __restrict__ g1pbh, short* __restrict__ g1pbl) {
  const int id = blockIdx.x * 256 + threadIdx.x;  // 32*256*20
  if (id >= 32 * 256 * 20) return;
  const int c16 = id % 20;
  const int PX = (id / 20) & 255;
  const int n = id / (20 * 256);
  const int Y = PX >> 4, X = PX & 15;
  const int r0 = Y * 64 + X * 2;
  const size_t base = ((size_t)n * 1024 + r0) * 160 + c16 * 8;
  const short8 h00 = *reinterpret_cast<const short8*>(f1bh + base);
  const short8 h01 = *reinterpret_cast<const short8*>(f1bh + base + 160);
  const short8 h10 = *reinterpret_cast<const short8*>(f1bh + base + 32 * 160);
  const short8 h11 = *reinterpret_cast<const short8*>(f1bh + base + 33 * 160);
  const short8 l00 = *reinterpret_cast<const short8*>(f1bl + base);
  const short8 l01 = *reinterpret_cast<const short8*>(f1bl + base + 160);
  const short8 l10 = *reinterpret_cast<const short8*>(f1bl + base + 32 * 160);
  const short8 l11 = *reinterpret_cast<const short8*>(f1bl + base + 33 * 160);
  short8 ho, lo;
#pragma unroll
  for (int j = 0; j < 8; ++j) {
    const float v = 0.25f * ((bff(h00[j]) + bff(l00[j])) + (bff(h01[j]) + bff(l01[j])) +
                             (bff(h10[j]) + bff(l10[j])) + (bff(h11[j]) + bff(l11[j])));
    const short h = bfh(v);
    ho[j] = h;
    lo[j] = bfh(v - bff(h));
  }
  const size_t ob = ((size_t)n * 256 + PX) * 160 + c16 * 8;
  *reinterpret_cast<short8*>(g1pbh + ob) = ho;
  *reinterpret_cast<short8*>(g1pbl + ob) = lo;
}

// ---------------------------------------------------------------------------
// Kernel 3: correlation via split-bf16 MFMA with gload staging
// (unchanged — verified; XCD swizzle kept)
// ---------------------------------------------------------------------------
__global__ __launch_bounds__(256)
void corr_kernel(const short* __restrict__ f0bh, const short* __restrict__ f0bl,
                 const short* __restrict__ f1bh, const short* __restrict__ f1bl,
                 const short* __restrict__ g1pbh, const short* __restrict__ g1pbl,
                 float* __restrict__ out) {
  __shared__ __align__(16) short f0L[2][32 * FSC];
  __shared__ __align__(16) short f1L[2][32 * FSC];
  __shared__ float S0[32 * 33];
  __shared__ float S1[2][32 * 17];
  const int flat = blockIdx.x;
  const int xcd = flat & 7;
  const int rr_ = flat >> 3;
  const int y = rr_ & 31;                 // 0..31
  const int n = (xcd << 2) | (rr_ >> 5);  // 0..31
  const int bb = n >> 3, q = n & 7;
  const int tid = threadIdx.x;
  const int lane = tid & 63;
  const int wave = __builtin_amdgcn_readfirstlane(tid >> 6);
  const int lr = lane & 15, kg = lane >> 4;
  const int xx = tid & 31;
  const int hi = tid >> 5;  // 0..7
  const float inv = 1.f / 160.f;
  const size_t obase = (size_t)(bb * 784 + q) * 1024 + (size_t)y * 32;

  // ---- stage f0 row: 20 gloads ----
  {
    const short* s0 = f0bh + ((size_t)n * 1024 + y * 32) * 160;
    const short* s1 = f0bl + ((size_t)n * 1024 + y * 32) * 160;
#pragma unroll
    for (int jj = 0; jj < 5; ++jj) {
      const int j = wave * 5 + jj;  // 0..19
      const int pl = j / 10, off = (j % 10) * 512;
      gload_lds16((pl ? s1 : s0) + off + lane * 8, &f0L[pl][off]);
    }
  }
  __syncthreads();

  // ---- hoist A-fragments ----
  const int mi0 = wave >> 1, ni0 = wave & 1;
  short8 a0h[5], a0l[5];
#pragma unroll
  for (int ks = 0; ks < 5; ++ks) {
    a0h[ks] = *reinterpret_cast<const short8*>(&f0L[0][(mi0 * 16 + lr) * FSC + ks * 32 + kg * 8]);
    a0l[ks] = *reinterpret_cast<const short8*>(&f0L[1][(mi0 * 16 + lr) * FSC + ks * 32 + kg * 8]);
  }

  // ---- level 0 ----
  for (int dyi = 0; dyi < 7; ++dyi) {
    const int yy = y + dyi - 3;
    const bool inr = (unsigned)yy < 32u;
    __syncthreads();
    if (inr) {
      const short* s0 = f1bh + ((size_t)n * 1024 + yy * 32) * 160;
      const short* s1 = f1bl + ((size_t)n * 1024 + yy * 32) * 160;
#pragma unroll
      for (int jj = 0; jj < 5; ++jj) {
        const int j = wave * 5 + jj;
        const int pl = j / 10, off = (j % 10) * 512;
        gload_lds16((pl ? s1 : s0) + off + lane * 8, &f1L[pl][off]);
      }
    }
    __syncthreads();
    if (inr) {
      f32x4 aA = {0.f, 0.f, 0.f, 0.f}, aB = aA, aC = aA;
#pragma unroll
      for (int ks = 0; ks < 5; ++ks) {
        const short8 bh = *reinterpret_cast<const short8*>(&f1L[0][(ni0 * 16 + lr) * FSC + ks * 32 + kg * 8]);
        const short8 bl = *reinterpret_cast<const short8*>(&f1L[1][(ni0 * 16 + lr) * FSC + ks * 32 + kg * 8]);
        aA = __builtin_amdgcn_mfma_f32_16x16x32_bf16(a0h[ks], bh, aA, 0, 0, 0);
        aB = __builtin_amdgcn_mfma_f32_16x16x32_bf16(a0h[ks], bl, aB, 0, 0, 0);
        aC = __builtin_amdgcn_mfma_f32_16x16x32_bf16(a0l[ks], bh, aC, 0, 0, 0);
      }
#pragma unroll
      for (int r = 0; r < 4; ++r)
        S0[(mi0 * 16 + kg * 4 + r) * 33 + ni0 * 16 + lr] = (aA[r] + aB[r]) + aC[r];
    }
    __syncthreads();
    if (hi < 7) {
      const int x2 = xx + hi - 3;
      const float val = (inr && (unsigned)x2 < 32u) ? S0[xx * 33 + x2] * inv : 0.f;
      out[obase + (size_t)(hi * 7 + dyi) * 8192 + xx] = val;
    }
  }

  // ---- level 1: corner dots on pooled planes, rolling S1 + fused combine ----
  short8 a1h[5], a1l[5];
  if (wave < 2) {
#pragma unroll
    for (int ks = 0; ks < 5; ++ks) {
      a1h[ks] = *reinterpret_cast<const short8*>(&f0L[0][(wave * 16 + lr) * FSC + ks * 32 + kg * 8]);
      a1l[ks] = *reinterpret_cast<const short8*>(&f0L[1][(wave * 16 + lr) * FSC + ks * 32 + kg * 8]);
    }
  }
  const int Y0 = (y >> 1) - 3;
  const float wy = (y & 1) ? 0.5f : 0.f;
  for (int v = 0; v < 8; ++v) {
    const int Y = Y0 + v;
    const bool inr = (unsigned)Y < 16u;
    __syncthreads();
    if (inr) {
      const short* s0 = g1pbh + ((size_t)n * 256 + Y * 16) * 160;
      const short* s1 = g1pbl + ((size_t)n * 256 + Y * 16) * 160;
#pragma unroll
      for (int jj = 0; jj < 3; ++jj) {
        const int j = wave * 3 + jj;  // 0..11
        if (j < 10) {
          const int pl = j / 5, off = (j % 5) * 512;
          gload_lds16((pl ? s1 : s0) + off + lane * 8, &f1L[pl][off]);
        }
      }
    }
    __syncthreads();
    if (wave < 2) {
      f32x4 aA = {0.f, 0.f, 0.f, 0.f}, aB = aA, aC = aA;
      if (inr) {
#pragma unroll
        for (int ks = 0; ks < 5; ++ks) {
          const short8 bh = *reinterpret_cast<const short8*>(&f1L[0][lr * FSC + ks * 32 + kg * 8]);
          const short8 bl = *reinterpret_cast<const short8*>(&f1L[1][lr * FSC + ks * 32 + kg * 8]);
          aA = __builtin_amdgcn_mfma_f32_16x16x32_bf16(a1h[ks], bh, aA, 0, 0, 0);
          aB = __builtin_amdgcn_mfma_f32_16x16x32_bf16(a1h[ks], bl, aB, 0, 0, 0);
          aC = __builtin_amdgcn_mfma_f32_16x16x32_bf16(a1l[ks], bh, aC, 0, 0, 0);
        }
      }
#pragma unroll
      for (int r = 0; r < 4; ++r)
        S1[v & 1][(wave * 16 + kg * 4 + r) * 17 + lr] = (aA[r] + aB[r]) + aC[r];
    }
    __syncthreads();
    if (v >= 1 && hi < 7) {
      const int dyi = v - 1;
      const int Xl = (xx >> 1) - 3 + hi;
      const int Xr = Xl + 1;
      const float* t0 = S1[(v - 1) & 1];
      const float* t1 = S1[v & 1];
      const float a00 = ((unsigned)Xl < 16u) ? t0[xx * 17 + Xl] : 0.f;
      const float a01 = ((unsigned)Xr < 16u) ? t0[xx * 17 + Xr] : 0.f;
      const float a10 = ((unsigned)Xl < 16u) ? t1[xx * 17 + Xl] : 0.f;
      const float a11 = ((unsigned)Xr < 16u) ? t1[xx * 17 + Xr] : 0.f;
      const float wx = (xx & 1) ? 0.5f : 0.f;
      const float val = ((1.f - wx) * ((1.f - wy) * a00 + wy * a10) +
                         wx * ((1.f - wy) * a01 + wy * a11)) * inv;
      out[obase + (size_t)(49 + hi * 7 + dyi) * 8192 + xx] = val;
    }
  }
}

// ---------------------------------------------------------------------------
extern "C" void kernel_launch(void* const* d_in, const int* in_sizes, int n_in,
                              void* d_out, int out_size, void* d_ws,
                              size_t ws_size, hipStream_t stream) {
  const float* x = (const float*)d_in[0];
  const float* w0 = (const float*)d_in[1];
  const float* w1 = (const float*)d_in[2];
  short* f0bh = (short*)d_ws;
  short* f0bl = f0bh + PL;
  short* f1bh = f0bl + PL;
  short* f1bl = f1bh + PL;
  short* g1pbh = f1bl + PL;
  short* g1pbl = g1pbh + PPL;
  short* wprep2 = g1pbh;  // overlapped: consumed by conv before pool writes
  float* out = (float*)d_out;

  wprep2_kernel<<<1040, 256, 0, stream>>>(w0, w1, wprep2);
  conv_fused<<<dim3(32, 4, 4), 512, 0, stream>>>(x, wprep2, f0bh, f0bl, f1bh, f1bl);
  pool_b<<<640, 256, 0, stream>>>(f1bh, f1bl, g1pbh, g1pbl);
  corr_kernel<<<1024, 256, 0, stream>>>(f0bh, f0bl, f1bh, f1bl, g1pbh, g1pbl, out);
}